// Round 10
// baseline (93.031 us; speedup 1.0000x reference)
//
#include <hip/hip_runtime.h>
#include <math.h>

// PhysicsConstraintLayer: per 10x10 block simplex/water-filling projection.
// tau-domain: e = exp(11x) (>=1 for x in [0,1)); root tau* solves
// G(tau) = sum(e - tau)+ = S', S' = sum(e_in) - 100.
// Out = log(max(e - (tau-1), 1)) / 11.
//
// R10 = R9 body with model-centered probes:
//  - per-lane closed-form estimate tau-hat from the log-uniform data model
//    (x ~ U[0,1) exactly, from setup_inputs): tau*(12 - ln tau) = 11*tau0+1,
//    solved by 2 fixed-point iterations (no cross-lane ops).
//  - probe band {0.70, 1.00, 1.40}*tau-hat replaces the fixed {2.8,5.5,11}*tau0
//    ladder (fixed ratios can't track tau*/tau0 which spans 1.3x..8x).
//  - convex piecewise-linear G: a probe on tau*'s segment gives the EXACT
//    root in one Newton step (tangent == segment); near tau* the segment
//    gaps are ~0.11*tau (log-uniform order stats), so a band around a good
//    center should leave ~1-2 refinement passes.
//  - refinement: N==prevN => active set unchanged (monotone tau => sets only
//    shrink) => G linear on the step => nt is that segment's exact root.
// Sentinels pv2/pv3 (R9 fix) keep phantom slots out of the active set at any
// tau. tau0<=0 fast path: full set consistent => tau*==tau0 exactly.

constexpr float kNorm    = 11.0f;
constexpr float kInvNorm = 1.0f / 11.0f;

#define LOMASK 0x00000000ffffffffULL

template<int CTRL>
__device__ __forceinline__ float dpp_add(float v) {
    const int t = __builtin_amdgcn_update_dpp(0, __float_as_int(v), CTRL, 0xF, 0xF, true);
    return v + __int_as_float(t);
}

// sum over each 32-lane half, result broadcast to all lanes of that half
__device__ __forceinline__ float reduce_half(float v) {
    v = dpp_add<0xB1>(v);    // quad_perm [1,0,3,2] : xor 1
    v = dpp_add<0x4E>(v);    // quad_perm [2,3,0,1] : xor 2
    v = dpp_add<0x141>(v);   // row_half_mirror     : sum over 8
    v = dpp_add<0x140>(v);   // row_mirror          : sum over 16
    const int t = __builtin_amdgcn_ds_swizzle(__float_as_int(v), 0x401F); // xor 16
    return v + __int_as_float(t);
}

__global__ __launch_bounds__(256) void pcl_r10_kernel(
    const float* __restrict__ pred,
    const float* __restrict__ inp,
    float* __restrict__ out,
    int n_blocks_total)
{
    const int tid  = blockIdx.x * 256 + threadIdx.x;
    const int lane = tid & 63;
    const int half = lane >> 5;
    const int l32  = lane & 31;

    const int blk = (tid >> 6) * 2 + half;          // this half's 10x10 block
    if (blk >= n_blocks_total) return;

    const int img  = blk / 6400;                    // 80x80 blocks per image
    const int rem  = blk - img * 6400;
    const int by   = rem / 80;
    const int bx   = rem - by * 80;
    const int base = img * 640000 + by * 8000 + bx * 10;

    // pair A: elements (2*l32, 2*l32+1); pair B: +64 (valid l32<18).
    const int eA = 2 * l32;
    const int rA = (eA * 205) >> 11;                // e/10 for e<128
    const int cA = eA - rA * 10;
    const int eB = eA + 64;
    const int rB = (eB * 205) >> 11;
    const int cB = eB - rB * 10;
    const bool vB = (l32 < 18);

    const int aA  = base + rA * 800 + cA;
    const int aBr = base + rB * 800 + cB;
    const int aB  = vB ? aBr : aA;                  // clamp for safe load

    const float2 PA = *(const float2*)(pred + aA);
    const float2 PB = *(const float2*)(pred + aB);
    const float2 IA = *(const float2*)(inp + aA);
    const float2 IB = *(const float2*)(inp + aB);

    const float p0 = __expf(PA.x * kNorm);
    const float p1 = __expf(PA.y * kNorm);
    const float p2 = vB ? __expf(PB.x * kNorm) : 0.0f;
    const float p3 = vB ? __expf(PB.y * kNorm) : 0.0f;
    const float si = __expf(IA.x * kNorm) + __expf(IA.y * kNorm)
                   + (vB ? (__expf(IB.x * kNorm) + __expf(IB.y * kNorm)) : 0.0f);

    const float S    = reduce_half(si) - 100.0f;    // S' = sum(e_in) - n
    const float sumP = reduce_half((p0 + p1) + (p2 + p3));

    const float tau0 = (sumP - S) * 0.01f;          // full-set Michelot step
    float tau = tau0;

    // solver sentinels: invalid slots can never enter the active set
    const float pv2 = vB ? p2 : -1.0e30f;
    const float pv3 = vB ? p3 : -1.0e30f;

    // ---- exact fast path: tau0 <= 0 < 1 <= min(p) => full set consistent ----
    if (!__all(tau0 <= 0.0f)) {
        float prevN = 100.0f;   // tau0 derives from the full set; if N stays
                                // 100 on pass 1, tau0 is already exact.

        // ---- per-lane model estimate (only meaningful when tau0 > 1) ----
        // tau-hat solves tau*(12 - ln tau) = 11*tau0 + 1 (log-uniform model).
        const bool hard = tau0 > 1.0f;              // A >= 12 > 0: log safe
        const float A   = 11.0f * tau0 + 1.0f;
        const float lnA = __logf(A);                // NaN-safe path: easy halves
        float den = fmaxf(12.0f - lnA, 1.0f);       // never select tauhat
        den = fmaxf(12.0f - (lnA - __logf(den)), 1.0f);
        const float tauhat = __fdividef(A, den);

        // ---- 3 model-centered probes (bounds valid from either side) ----
        {
            const float mult[3] = {0.70f, 1.00f, 1.40f};
            #pragma unroll
            for (int t = 0; t < 3; ++t) {
                const float th = hard ? tauhat * mult[t] : 3.0e38f;
                const float d0 = fmaxf(p0  - th, 0.0f);
                const float d1 = fmaxf(p1  - th, 0.0f);
                const float d2 = fmaxf(pv2 - th, 0.0f);
                const float d3 = fmaxf(pv3 - th, 0.0f);
                const unsigned long long b0 = __ballot(d0 > 0.0f);
                const unsigned long long b1 = __ballot(d1 > 0.0f);
                const unsigned long long b2 = __ballot(d2 > 0.0f);
                const unsigned long long b3 = __ballot(d3 > 0.0f);
                const float G = reduce_half((d0 + d1) + (d2 + d3));
                const int cl = __popcll(b0 & LOMASK) + __popcll(b1 & LOMASK)
                             + __popcll(b2 & LOMASK) + __popcll(b3 & LOMASK);
                const int ch = __popcll(b0 >> 32) + __popcll(b1 >> 32)
                             + __popcll(b2 >> 32) + __popcll(b3 >> 32);
                const float N = half ? (float)ch : (float)cl;
                if (N > 0.5f) {
                    const float cand = th + __fdividef(G - S, N);
                    if (cand > tau) { tau = cand; prevN = N; }
                }
            }
        }

        // ---- exact Newton/Michelot refinement (fmax form; monotone) ----
        #pragma unroll 1
        for (int it = 0; it < 50; ++it) {
            const float d0 = fmaxf(p0  - tau, 0.0f);
            const float d1 = fmaxf(p1  - tau, 0.0f);
            const float d2 = fmaxf(pv2 - tau, 0.0f);
            const float d3 = fmaxf(pv3 - tau, 0.0f);
            const unsigned long long b0 = __ballot(d0 > 0.0f);
            const unsigned long long b1 = __ballot(d1 > 0.0f);
            const unsigned long long b2 = __ballot(d2 > 0.0f);
            const unsigned long long b3 = __ballot(d3 > 0.0f);
            const float G = reduce_half((d0 + d1) + (d2 + d3));
            const int cl = __popcll(b0 & LOMASK) + __popcll(b1 & LOMASK)
                         + __popcll(b2 & LOMASK) + __popcll(b3 & LOMASK);
            const int ch = __popcll(b0 >> 32) + __popcll(b1 >> 32)
                         + __popcll(b2 >> 32) + __popcll(b3 >> 32);
            const float N  = half ? (float)ch : (float)cl;
            const float nt = (N > 0.5f) ? tau + __fdividef(G - S, N) : tau;
            const bool stable = (N == prevN) || (N < 0.5f) || (nt - tau <= 0.02f);
            tau = fmaxf(tau, nt);
            if (__all(stable)) break;
            prevN = N;
        }
    }

    // ---- epilogue: out = log(max(e - (tau-1), 1)) / 11 ----
    const float tm1 = tau - 1.0f;
    float2 OA;
    OA.x = __logf(fmaxf(p0 - tm1, 1.0f)) * kInvNorm;
    OA.y = __logf(fmaxf(p1 - tm1, 1.0f)) * kInvNorm;
    *(float2*)(out + aA) = OA;
    if (vB) {
        float2 OB;
        OB.x = __logf(fmaxf(p2 - tm1, 1.0f)) * kInvNorm;
        OB.y = __logf(fmaxf(p3 - tm1, 1.0f)) * kInvNorm;
        *(float2*)(out + aBr) = OB;
    }
}

extern "C" void kernel_launch(void* const* d_in, const int* in_sizes, int n_in,
                              void* d_out, int out_size, void* d_ws, size_t ws_size,
                              hipStream_t stream) {
    const float* pred = (const float*)d_in[0];
    const float* inp  = (const float*)d_in[1];
    float* out        = (float*)d_out;

    const int n_images = in_sizes[0] / (800 * 800);   // 48
    const int n_blocks = n_images * 6400;             // 307200
    const int waves    = (n_blocks + 1) / 2;          // 2 blocks per wave
    const int wgs      = (waves + 3) / 4;             // 4 waves per 256-thr WG

    pcl_r10_kernel<<<wgs, 256, 0, stream>>>(pred, inp, out, n_blocks);
}

// Round 11
// 89.012 us; speedup vs baseline: 1.0451x; 1.0451x over previous
//
#include <hip/hip_runtime.h>
#include <math.h>

// PhysicsConstraintLayer: per 10x10 block simplex/water-filling projection.
// tau-domain: e = exp(11x) (>=1 for x in [0,1)); root tau* solves
// G(tau) = sum(e - tau)+ = S', S' = sum(e_in) - 100.
// Out = log(max(e - (tau-1), 1)) / 11.
//
// R11 = R5 champion solver config (fixed {2.8,5.5,11}*tau0 probe ladder,
// 86.0 us best measured) in R9's fmax-form + sentinel hygiene, plus a
// 3D-grid addressing diet:
//   grid = (10, 80, 48): img = blockIdx.z, by = blockIdx.y (SGPR, free),
//   bx = blockIdx.x*8 + halfwave-region. No /6400 or /80 magic-muls, no
//   bounds check (grid covers exactly 48*80*80 blocks).

constexpr float kNorm    = 11.0f;
constexpr float kInvNorm = 1.0f / 11.0f;

#define LOMASK 0x00000000ffffffffULL

template<int CTRL>
__device__ __forceinline__ float dpp_add(float v) {
    const int t = __builtin_amdgcn_update_dpp(0, __float_as_int(v), CTRL, 0xF, 0xF, true);
    return v + __int_as_float(t);
}

// sum over each 32-lane half, result broadcast to all lanes of that half
__device__ __forceinline__ float reduce_half(float v) {
    v = dpp_add<0xB1>(v);    // quad_perm [1,0,3,2] : xor 1
    v = dpp_add<0x4E>(v);    // quad_perm [2,3,0,1] : xor 2
    v = dpp_add<0x141>(v);   // row_half_mirror     : sum over 8
    v = dpp_add<0x140>(v);   // row_mirror          : sum over 16
    const int t = __builtin_amdgcn_ds_swizzle(__float_as_int(v), 0x401F); // xor 16
    return v + __int_as_float(t);
}

__global__ __launch_bounds__(256) void pcl_r11_kernel(
    const float* __restrict__ pred,
    const float* __restrict__ inp,
    float* __restrict__ out)
{
    const int tx   = threadIdx.x;
    const int half = (tx >> 5) & 1;
    const int l32  = tx & 31;

    // block coords: img/by from SGPR block indices; bx = bid.x*8 + region
    const int region = tx >> 5;                       // 0..7 half-wave in WG
    const int bx     = blockIdx.x * 8 + region;
    const int base   = (int)blockIdx.z * 640000 + (int)blockIdx.y * 8000 + bx * 10;

    // pair A: elements (2*l32, 2*l32+1); pair B: +64 (valid l32<18).
    const int eA = 2 * l32;
    const int rA = (eA * 205) >> 11;                  // e/10 for e<128
    const int cA = eA - rA * 10;
    const int eB = eA + 64;
    const int rB = (eB * 205) >> 11;
    const int cB = eB - rB * 10;
    const bool vB = (l32 < 18);

    const int aA  = base + rA * 800 + cA;
    const int aBr = base + rB * 800 + cB;
    const int aB  = vB ? aBr : aA;                    // clamp for safe load

    const float2 PA = *(const float2*)(pred + aA);
    const float2 PB = *(const float2*)(pred + aB);
    const float2 IA = *(const float2*)(inp + aA);
    const float2 IB = *(const float2*)(inp + aB);

    const float p0 = __expf(PA.x * kNorm);
    const float p1 = __expf(PA.y * kNorm);
    const float p2 = vB ? __expf(PB.x * kNorm) : 0.0f;
    const float p3 = vB ? __expf(PB.y * kNorm) : 0.0f;
    const float si = __expf(IA.x * kNorm) + __expf(IA.y * kNorm)
                   + (vB ? (__expf(IB.x * kNorm) + __expf(IB.y * kNorm)) : 0.0f);

    const float S    = reduce_half(si) - 100.0f;      // S' = sum(e_in) - n
    const float sumP = reduce_half((p0 + p1) + (p2 + p3));

    const float tau0 = (sumP - S) * 0.01f;            // full-set Michelot step
    float tau = tau0;

    // solver sentinels: invalid slots can never enter the active set
    const float pv2 = vB ? p2 : -1.0e30f;
    const float pv3 = vB ? p3 : -1.0e30f;

    // ---- exact fast path: tau0 <= 0 < 1 <= min(p) => full set consistent ----
    if (!__all(tau0 <= 0.0f)) {
        float prevN = 100.0f;   // tau0 derives from the full set

        // ---- 3 fixed-ratio adaptive probes (R5 ladder; either-side bounds) --
        {
            const float mult[3] = {2.8f, 5.5f, 11.0f};
            #pragma unroll
            for (int t = 0; t < 3; ++t) {
                // easy halves (tau0<=0): huge th -> N=0 -> probe inert
                const float th = (tau0 > 0.0f) ? tau0 * mult[t] : 3.0e38f;
                const float d0 = fmaxf(p0  - th, 0.0f);
                const float d1 = fmaxf(p1  - th, 0.0f);
                const float d2 = fmaxf(pv2 - th, 0.0f);
                const float d3 = fmaxf(pv3 - th, 0.0f);
                const unsigned long long b0 = __ballot(d0 > 0.0f);
                const unsigned long long b1 = __ballot(d1 > 0.0f);
                const unsigned long long b2 = __ballot(d2 > 0.0f);
                const unsigned long long b3 = __ballot(d3 > 0.0f);
                const float G = reduce_half((d0 + d1) + (d2 + d3));
                const int cl = __popcll(b0 & LOMASK) + __popcll(b1 & LOMASK)
                             + __popcll(b2 & LOMASK) + __popcll(b3 & LOMASK);
                const int ch = __popcll(b0 >> 32) + __popcll(b1 >> 32)
                             + __popcll(b2 >> 32) + __popcll(b3 >> 32);
                const float N = half ? (float)ch : (float)cl;
                if (N > 0.5f) {
                    const float cand = th + __fdividef(G - S, N);
                    if (cand > tau) { tau = cand; prevN = N; }
                }
            }
        }

        // ---- exact Newton/Michelot refinement (fmax form; monotone) ----
        #pragma unroll 1
        for (int it = 0; it < 50; ++it) {
            const float d0 = fmaxf(p0  - tau, 0.0f);
            const float d1 = fmaxf(p1  - tau, 0.0f);
            const float d2 = fmaxf(pv2 - tau, 0.0f);
            const float d3 = fmaxf(pv3 - tau, 0.0f);
            const unsigned long long b0 = __ballot(d0 > 0.0f);
            const unsigned long long b1 = __ballot(d1 > 0.0f);
            const unsigned long long b2 = __ballot(d2 > 0.0f);
            const unsigned long long b3 = __ballot(d3 > 0.0f);
            const float G = reduce_half((d0 + d1) + (d2 + d3));
            const int cl = __popcll(b0 & LOMASK) + __popcll(b1 & LOMASK)
                         + __popcll(b2 & LOMASK) + __popcll(b3 & LOMASK);
            const int ch = __popcll(b0 >> 32) + __popcll(b1 >> 32)
                         + __popcll(b2 >> 32) + __popcll(b3 >> 32);
            const float N  = half ? (float)ch : (float)cl;
            const float nt = (N > 0.5f) ? tau + __fdividef(G - S, N) : tau;
            const bool stable = (N == prevN) || (N < 0.5f) || (nt - tau <= 0.02f);
            tau = fmaxf(tau, nt);
            if (__all(stable)) break;
            prevN = N;
        }
    }

    // ---- epilogue: out = log(max(e - (tau-1), 1)) / 11 ----
    const float tm1 = tau - 1.0f;
    float2 OA;
    OA.x = __logf(fmaxf(p0 - tm1, 1.0f)) * kInvNorm;
    OA.y = __logf(fmaxf(p1 - tm1, 1.0f)) * kInvNorm;
    *(float2*)(out + aA) = OA;
    if (vB) {
        float2 OB;
        OB.x = __logf(fmaxf(p2 - tm1, 1.0f)) * kInvNorm;
        OB.y = __logf(fmaxf(p3 - tm1, 1.0f)) * kInvNorm;
        *(float2*)(out + aBr) = OB;
    }
}

extern "C" void kernel_launch(void* const* d_in, const int* in_sizes, int n_in,
                              void* d_out, int out_size, void* d_ws, size_t ws_size,
                              hipStream_t stream) {
    const float* pred = (const float*)d_in[0];
    const float* inp  = (const float*)d_in[1];
    float* out        = (float*)d_out;

    // 48 images x 80 block-rows x 80 block-cols; 8 blocks per 256-thread WG
    // (2 per wave). Grid covers the domain exactly: no bounds checks.
    dim3 grid(10, 80, 48);
    pcl_r11_kernel<<<grid, 256, 0, stream>>>(pred, inp, out);
}